// Round 3
// baseline (169.023 us; speedup 1.0000x reference)
//
#include <hip/hip_runtime.h>
#include <hip/hip_cooperative_groups.h>
#include <math.h>

namespace cg = cooperative_groups;

#define NP   128
#define DIM  2048
#define NBLK 64
#define NTHR 256

// Single cooperative kernel: 64 blocks x 256 threads, 5 grid syncs.
// ws layout: Ppart[64][16384] | P[16384] | dMsd[16384] | A[16384] | scal[4]
__global__ __launch_bounds__(NTHR) void stein_fused(
    const float* __restrict__ var, const float* __restrict__ grad,
    float* __restrict__ out, float* __restrict__ Ppart,
    float* __restrict__ P, float* __restrict__ dMsd,
    float* __restrict__ A, float* __restrict__ scal)
{
    cg::grid_group grid = cg::this_grid();

    __shared__ float smem[16512];      // 64.5 KB: S1 At/Bt | S3/S5 P[128][129] | S6 A[16][128]
    __shared__ float kern_s[2 * NP];
    __shared__ float wsum[4];
    __shared__ unsigned usmall[8];     // warp counts [0..3], selected prefix [4]

    const int tid = threadIdx.x;
    const int b   = blockIdx.x;

    //===== S1: P partial: block b handles K-chunk [32b, 32b+32) ================
    {
        float* At = smem;              // [32][132] (k-major, padded)
        float* Bt = smem + 32 * 132;
        const int k0 = b * 32;
        for (int c = tid; c < 1024; c += NTHR) {
            const int row = c >> 3;
            const int kq  = (c & 7) << 2;
            const float4 a = *(const float4*)(var  + row * DIM + k0 + kq);
            const float4 g = *(const float4*)(grad + row * DIM + k0 + kq);
            At[(kq + 0) * 132 + row] = a.x; At[(kq + 1) * 132 + row] = a.y;
            At[(kq + 2) * 132 + row] = a.z; At[(kq + 3) * 132 + row] = a.w;
            Bt[(kq + 0) * 132 + row] = g.x; Bt[(kq + 1) * 132 + row] = g.y;
            Bt[(kq + 2) * 132 + row] = g.z; Bt[(kq + 3) * 132 + row] = g.w;
        }
        __syncthreads();

        const int tx = tid & 15;
        const int ty = tid >> 4;
        float acc[8][8] = {};
        #pragma unroll 4
        for (int kk = 0; kk < 32; ++kk) {
            float a[8], g[8];
            #pragma unroll
            for (int i = 0; i < 8; ++i) a[i] = At[kk * 132 + ty + 16 * i];
            #pragma unroll
            for (int j = 0; j < 8; ++j) g[j] = Bt[kk * 132 + tx + 16 * j];
            #pragma unroll
            for (int i = 0; i < 8; ++i)
                #pragma unroll
                for (int j = 0; j < 8; ++j)
                    acc[i][j] = fmaf(a[i], g[j], acc[i][j]);
        }
        float* dst = Ppart + b * (NP * NP);
        #pragma unroll
        for (int i = 0; i < 8; ++i)
            #pragma unroll
            for (int j = 0; j < 8; ++j)
                dst[(ty + 16 * i) * NP + tx + 16 * j] = acc[i][j];
    }
    grid.sync();

    //===== S2: reduce 64 partials -> P =========================================
    {
        const int tg = b * NTHR + tid;           // 0..16383
        float s = 0.f;
        #pragma unroll 8
        for (int p = 0; p < NBLK; ++p) s += Ppart[p * (NP * NP) + tg];
        P[tg] = s;
    }
    grid.sync();

    //===== S3: stage P into LDS (pad 129) + dMsd ==============================
    float my_dmsd;
    {
        for (int f = tid; f < 4096; f += NTHR) {     // 4096 float4 = all of P
            const float4 v4 = *(const float4*)(P + 4 * f);
            const int r = f >> 5;
            const int c = (4 * f) & 127;
            smem[r * 129 + c + 0] = v4.x; smem[r * 129 + c + 1] = v4.y;
            smem[r * 129 + c + 2] = v4.z; smem[r * 129 + c + 3] = v4.w;
        }
        __syncthreads();
        const int i = 2 * b + (tid >> 7);
        const int j = tid & 127;
        float acc = 0.f;
        #pragma unroll 4
        for (int k = 0; k < NP; ++k) {
            const float d = smem[i * 129 + k] - smem[j * 129 + k];
            acc = fmaf(d, d, acc);
        }
        my_dmsd = acc * (1.0f / 128.0f);
        dMsd[b * NTHR + tid] = my_dmsd;              // == dMsd[i][j]
    }
    grid.sync();

    //===== S4: exact median, rank 8192 (block 0 only) ==========================
    // nearest-rank: round-half-even(0.5*16383)=8192; uint order == float order (v>=0)
    if (b == 0) {
        unsigned v[64];
        #pragma unroll
        for (int u = 0; u < 64; ++u) v[u] = __float_as_uint(dMsd[u * NTHR + tid]);
        if (tid == 0) usmall[4] = 0u;
        __syncthreads();
        unsigned lo = 0u;
        for (int bit = 30; bit >= 0; --bit) {
            const unsigned mid = lo | (1u << bit);
            unsigned cnt = 0;
            #pragma unroll
            for (int u = 0; u < 64; ++u) cnt += (v[u] < mid) ? 1u : 0u;
            #pragma unroll
            for (int o = 32; o > 0; o >>= 1) cnt += __shfl_down(cnt, o);
            if ((tid & 63) == 0) usmall[tid >> 6] = cnt;
            __syncthreads();
            if (tid == 0) {
                const unsigned total = usmall[0] + usmall[1] + usmall[2] + usmall[3];
                if (total <= 8192u) usmall[4] = mid;
            }
            __syncthreads();
            lo = usmall[4];
        }
        if (tid == 0) {
            const float med = __uint_as_float(lo);
            const float h = med * med * (1.0f / 4.852030263919617f);  // / ln(128)
            scal[0] = med;
            scal[1] = 1.0f / (2.0f * h);
            scal[2] = 1.0f / h;
        }
    }
    grid.sync();

    //===== S5: A = kern + (1/(128h)) (kern@P - rowsum*P); P still in LDS =======
    {
        const float inv2h = scal[1];
        const float invh  = scal[2];
        const int h = tid >> 7;
        const int i = 2 * b + h;
        const int j = tid & 127;
        const float kv = expf(-my_dmsd * inv2h);
        kern_s[h * NP + j] = kv;
        float s = kv;
        #pragma unroll
        for (int o = 32; o > 0; o >>= 1) s += __shfl_down(s, o);
        if ((tid & 63) == 0) wsum[tid >> 6] = s;
        __syncthreads();
        const float rowsum = wsum[2 * h] + wsum[2 * h + 1];
        float acc = 0.f;
        #pragma unroll 4
        for (int m = 0; m < NP; ++m)
            acc = fmaf(kern_s[h * NP + m], smem[m * 129 + j], acc);
        A[i * NP + j] = kv + invh * (1.0f / 128.0f) * (acc - rowsum * smem[i * 129 + j]);
    }
    grid.sync();

    //===== S6: out = A @ grad ==================================================
    {
        const int rg = b >> 3;      // 8 row groups x 16 rows
        const int cgp = b & 7;      // 8 col groups x 256 cols
        for (int f = tid; f < 512; f += NTHR) {      // stage A[16][128] -> smem
            const float4 a4 = *(const float4*)(A + rg * 16 * NP + 4 * f);
            smem[4 * f + 0] = a4.x; smem[4 * f + 1] = a4.y;
            smem[4 * f + 2] = a4.z; smem[4 * f + 3] = a4.w;
        }
        __syncthreads();
        const int c = cgp * 256 + tid;
        float acc[16] = {};
        for (int m = 0; m < NP; ++m) {
            const float g = grad[m * DIM + c];
            #pragma unroll
            for (int r = 0; r < 16; ++r)
                acc[r] = fmaf(smem[r * NP + m], g, acc[r]);
        }
        #pragma unroll
        for (int r = 0; r < 16; ++r)
            out[(rg * 16 + r) * DIM + c] = acc[r];
    }
}

// ---------------------------------------------------------------------------
extern "C" void kernel_launch(void* const* d_in, const int* in_sizes, int n_in,
                              void* d_out, int out_size, void* d_ws, size_t ws_size,
                              hipStream_t stream) {
    const float* var  = (const float*)d_in[0];
    const float* grad = (const float*)d_in[1];
    float* out = (float*)d_out;

    float* Ppart = (float*)d_ws;                       // 64*16384 f32 = 4 MB
    float* P     = Ppart + NBLK * NP * NP;
    float* dMsd  = P + NP * NP;
    float* A     = dMsd + NP * NP;
    float* scal  = A + NP * NP;

    void* args[] = { (void*)&var, (void*)&grad, (void*)&out,
                     (void*)&Ppart, (void*)&P, (void*)&dMsd,
                     (void*)&A, (void*)&scal };
    hipLaunchCooperativeKernel((const void*)stein_fused, dim3(NBLK), dim3(NTHR),
                               args, 0, stream);
}